// Round 14
// baseline (261.147 us; speedup 1.0000x reference)
//
#include <hip/hip_runtime.h>

// ChebConv x2: N=100000, E=1600000, K=3, IN=128, HID=64, OUT=40
// Round 14 = round 13 +
//  (1) props: 4 nodes/wave (16-lane quarter each, 2 grp x 8 lanes), unroll
//      x4 -> 4 gathers in flight; butterfly 1 round (mask 8).
//  (2) GEMMs: 2 row-tiles per wave -> each Wfrag B-fragment load feeds 2
//      MFMAs (Wfrag L2 stream halves).
//  (3) merged wfrag kernel; merged passC+passC2.
//  CSR radix build w/ XCD-major cursors, bf16 residuals: round 12/13.

#define NBLK_PART 1024
#define MAXBUK 1024

typedef __attribute__((ext_vector_type(8))) short bf16x8;
typedef __attribute__((ext_vector_type(4))) float f32x4;

__device__ inline unsigned short f2bf(float f) {
  unsigned u = __float_as_uint(f);
  return (unsigned short)((u + 0x7FFFu + ((u >> 16) & 1u)) >> 16);
}
__device__ inline unsigned pk2(float a, float b) {
  return (unsigned)f2bf(a) | ((unsigned)f2bf(b) << 16);
}
__device__ inline float bflo(unsigned u) { return __uint_as_float(u << 16); }
__device__ inline float bfhi(unsigned u) { return __uint_as_float(u & 0xffff0000u); }

// XCD-major block permutation for cursor ranges (heuristic: XCD = b % 8)
__device__ inline int permb(int b) { return ((b & 7) << 7) | (b >> 3); }

// pass A: per-block LDS histograms of dst>>7 and src>>7 (no global atomics)
__global__ __launch_bounds__(256) void k_passA(const int* __restrict__ src,
                                               const int* __restrict__ dst, int E, int cpb,
                                               int* __restrict__ histGd,
                                               int* __restrict__ histGs, int nbuk) {
  __shared__ int histD[MAXBUK], histS[MAXBUK];
  const int t = threadIdx.x, b = blockIdx.x;
  for (int k = t; k < nbuk; k += 256) {
    histD[k] = 0;
    histS[k] = 0;
  }
  __syncthreads();
  const int e0 = b * cpb;
  const int e1 = min(E, e0 + cpb);
  for (int e = e0 + t; e < e1; e += 256) {
    atomicAdd(&histD[dst[e] >> 7], 1);
    atomicAdd(&histS[src[e] >> 7], 1);
  }
  __syncthreads();
  const int bp = permb(b);
  for (int k = t; k < nbuk; k += 256) {
    histGd[k * NBLK_PART + bp] = histD[k];
    histGs[k * NBLK_PART + bp] = histS[k];
  }
}

// per bucket: exclusive scan over the 1024 partition slots; grid = 2*nbuk
__global__ __launch_bounds__(256) void k_scanA(int* __restrict__ histGd,
                                               int* __restrict__ histGs,
                                               int* __restrict__ buktotD,
                                               int* __restrict__ buktotS, int nbuk) {
  __shared__ int sh[256];
  const int bb = blockIdx.x, t = threadIdx.x;
  int* hist = (bb < nbuk) ? histGd : histGs;
  int* tot = (bb < nbuk) ? buktotD : buktotS;
  const int b = (bb < nbuk) ? bb : bb - nbuk;
  const int base = b * NBLK_PART;
  int v[4];
  int s = 0;
#pragma unroll
  for (int i = 0; i < 4; i++) {
    v[i] = hist[base + t * 4 + i];
    s += v[i];
  }
  int run = s;
  sh[t] = run;
  __syncthreads();
  for (int off = 1; off < 256; off <<= 1) {
    int x = (t >= off) ? sh[t - off] : 0;
    __syncthreads();
    run += x;
    sh[t] = run;
    __syncthreads();
  }
  if (t == 255) tot[b] = run;
  int p = run - s;
#pragma unroll
  for (int i = 0; i < 4; i++) {
    hist[base + t * 4 + i] = p;
    p += v[i];
  }
}

// exclusive scan in place of two arrays (grid=2), nb <= 1024
__global__ __launch_bounds__(256) void k_scanB(int* __restrict__ aD, int* __restrict__ aS,
                                               int nb) {
  __shared__ int sh[256];
  int* a = (blockIdx.x == 0) ? aD : aS;
  const int t = threadIdx.x;
  int v[4];
  int s = 0;
#pragma unroll
  for (int i = 0; i < 4; i++) {
    int idx = t * 4 + i;
    v[i] = (idx < nb) ? a[idx] : 0;
    s += v[i];
  }
  int run = s;
  sh[t] = run;
  __syncthreads();
  for (int off = 1; off < 256; off <<= 1) {
    int x = (t >= off) ? sh[t - off] : 0;
    __syncthreads();
    run += x;
    sh[t] = run;
    __syncthreads();
  }
  int p = run - s;
#pragma unroll
  for (int i = 0; i < 4; i++) {
    int idx = t * 4 + i;
    if (idx < nb) a[idx] = p;
    p += v[i];
  }
}

// pass B: scatter (src<<7)|(dst&127) into dst-bucket order AND (src&127)
// bytes into src-bucket order, LDS cursors only; XCD-major cursor bases
__global__ __launch_bounds__(256) void k_passB(const int* __restrict__ src,
                                               const int* __restrict__ dst, int E, int cpb,
                                               const int* __restrict__ histGd,
                                               const int* __restrict__ histGs,
                                               const int* __restrict__ bukoffD,
                                               const int* __restrict__ bukoffS, int nbuk,
                                               unsigned int* __restrict__ packed,
                                               unsigned char* __restrict__ pksrc) {
  __shared__ int curD[MAXBUK], curS[MAXBUK];
  const int t = threadIdx.x, b = blockIdx.x;
  const int bp = permb(b);
  for (int k = t; k < nbuk; k += 256) {
    curD[k] = bukoffD[k] + histGd[k * NBLK_PART + bp];
    curS[k] = bukoffS[k] + histGs[k * NBLK_PART + bp];
  }
  __syncthreads();
  const int e0 = b * cpb;
  const int e1 = min(E, e0 + cpb);
  for (int e = e0 + t; e < e1; e += 256) {
    int s = src[e], d = dst[e];
    int slot = atomicAdd(&curD[d >> 7], 1);
    packed[slot] = ((unsigned)s << 7) | (unsigned)(d & 127);
    int slot2 = atomicAdd(&curS[s >> 7], 1);
    pksrc[slot2] = (unsigned char)(s & 127);
  }
}

// merged pass C (blocks [0,nbuk): CSR finalize from dst buckets) and
// pass C2 (blocks [nbuk,2nbuk): dinv from src-bucket bytes)
__global__ __launch_bounds__(256) void k_passCM(const unsigned int* __restrict__ packed,
                                                const unsigned char* __restrict__ pksrc,
                                                const int* __restrict__ bukoffD,
                                                const int* __restrict__ bukoffS, int nbuk,
                                                int E, int n, int* __restrict__ csr_src,
                                                int* __restrict__ row_ptr,
                                                float* __restrict__ dinv) {
  __shared__ int cnt[128], scn[128], cur[128];
  const int t = threadIdx.x;
  if (blockIdx.x < nbuk) {
    const int b = blockIdx.x;
    if (t < 128) cnt[t] = 0;
    __syncthreads();
    const int e0 = bukoffD[b];
    const int e1 = (b + 1 < nbuk) ? bukoffD[b + 1] : E;
    for (int e = e0 + t; e < e1; e += 256) atomicAdd(&cnt[packed[e] & 127], 1);
    __syncthreads();
    if (t < 128) scn[t] = cnt[t];
    __syncthreads();
    for (int off = 1; off < 128; off <<= 1) {
      int x = (t < 128 && t >= off) ? scn[t - off] : 0;
      __syncthreads();
      if (t < 128) scn[t] += x;
      __syncthreads();
    }
    if (t < 128) {
      int start = e0 + scn[t] - cnt[t];
      cur[t] = start;
      int node = (b << 7) + t;
      if (node < n) row_ptr[node] = start;
    }
    if (b == 0 && t == 0) row_ptr[n] = E;
    __syncthreads();
    for (int e = e0 + t; e < e1; e += 256) {
      unsigned v = packed[e];
      int slot = atomicAdd(&cur[v & 127], 1);
      csr_src[slot] = (int)(v & ~127u);  // src*128 = byte offset of bf16[64] row
    }
  } else {
    const int b = blockIdx.x - nbuk;
    if (t < 128) cnt[t] = 0;
    __syncthreads();
    const int e0 = bukoffS[b];
    const int e1 = (b + 1 < nbuk) ? bukoffS[b + 1] : E;
    for (int e = e0 + t; e < e1; e += 256) atomicAdd(&cnt[pksrc[e]], 1);
    __syncthreads();
    if (t < 128) {
      int node = (b << 7) + t;
      if (node < n) {
        int d = cnt[t];
        dinv[node] = (d > 0) ? rsqrtf((float)d) : 0.f;
      }
    }
  }
}

// pre-swizzle effective weights into MFMA B-fragment order, bf16 (merged)
__device__ inline void wfrag_emit(const float* __restrict__ W,
                                  unsigned short* __restrict__ Wfrag, int INF, int OUTC,
                                  int NT, int idx) {
  int lane = idx & 63;
  int nt = (idx >> 6) % NT;
  int ks = idx / (64 * NT);
  int col = nt * 16 + (lane & 15);
  int kb = ks * 32 + (lane >> 4) * 8;
  unsigned short o8[8];
#pragma unroll
  for (int j = 0; j < 8; j++) {
    int k = kb + j;
    float v = 0.f;
    if (col < 3 * OUTC) {
      int m = col / OUTC, o = col - m * OUTC;
      if (m == 0)      v = W[(0 * INF + k) * OUTC + o] - W[(2 * INF + k) * OUTC + o];
      else if (m == 1) v = W[(1 * INF + k) * OUTC + o];
      else             v = 2.f * W[(2 * INF + k) * OUTC + o];
    }
    o8[j] = f2bf(v);
  }
  uint4 r;
  r.x = (unsigned)o8[0] | ((unsigned)o8[1] << 16);
  r.y = (unsigned)o8[2] | ((unsigned)o8[3] << 16);
  r.z = (unsigned)o8[4] | ((unsigned)o8[5] << 16);
  r.w = (unsigned)o8[6] | ((unsigned)o8[7] << 16);
  *reinterpret_cast<uint4*>(Wfrag + (size_t)idx * 8) = r;
}

__global__ void k_wfragM(const float* __restrict__ W1, unsigned short* __restrict__ Wf1,
                         const float* __restrict__ W2, unsigned short* __restrict__ Wf2) {
  int idx = blockIdx.x * 256 + threadIdx.x;
  const int tot1 = 4 * 12 * 64;
  const int tot2 = 2 * 8 * 64;
  if (idx < tot1)
    wfrag_emit(W1, Wf1, 128, 64, 12, idx);
  else if (idx < tot1 + tot2)
    wfrag_emit(W2, Wf2, 64, 40, 8, idx - tot1);
}

// LDS-free MFMA GEMM, 2 row-tiles per wave (32 rows), all-bf16 split epilogue:
//   each Wfrag B-fragment load feeds 2 MFMAs.
//   cols [0,C1) -> O0 bf16 S0; [C1,C2) -> O1 bf16 S1; [C2,C3) -> O2 bf16 S2
//   (O2 scaled by dinv[row]).
template <int INF, int NT, bool XBF16, int XSTR, int C1, int C2, int C3, int S0, int S1,
          int S2>
__global__ __launch_bounds__(256) void k_gemm_mfma(const void* __restrict__ Xv,
                                                   const unsigned short* __restrict__ Wfrag,
                                                   const float* __restrict__ dinv,
                                                   unsigned short* __restrict__ O0,
                                                   unsigned short* __restrict__ O1,
                                                   unsigned short* __restrict__ O2, int n) {
  constexpr int KSTEPS = INF / 32;
  const int lane = threadIdx.x & 63;
  const int w = threadIdx.x >> 6;
  const int base = blockIdx.x * 128 + 32 * w;  // this wave's 32-row tile
  const int k8 = (lane >> 4) * 8;
  union U16 {
    uint4 u;
    bf16x8 b;
  };
  bf16x8 afrag[2][KSTEPS];
#pragma unroll
  for (int t = 0; t < 2; t++) {
    const int arow = base + t * 16 + (lane & 15);
    const bool ok = arow < n;
    if (XBF16) {
      const unsigned short* sp =
          (const unsigned short*)Xv + (size_t)(ok ? arow : 0) * XSTR + k8;
#pragma unroll
      for (int ks = 0; ks < KSTEPS; ks++) {
        U16 u;
        u.u = make_uint4(0, 0, 0, 0);
        if (ok) u.u = *reinterpret_cast<const uint4*>(sp + ks * 32);
        afrag[t][ks] = u.b;
      }
    } else {
      const float* sp = (const float*)Xv + (size_t)(ok ? arow : 0) * XSTR + k8;
#pragma unroll
      for (int ks = 0; ks < KSTEPS; ks++) {
        float4 va = make_float4(0.f, 0.f, 0.f, 0.f), vb = va;
        if (ok) {
          va = *reinterpret_cast<const float4*>(sp + ks * 32);
          vb = *reinterpret_cast<const float4*>(sp + ks * 32 + 4);
        }
        U16 u;
        u.u.x = pk2(va.x, va.y);
        u.u.y = pk2(va.z, va.w);
        u.u.z = pk2(vb.x, vb.y);
        u.u.w = pk2(vb.z, vb.w);
        afrag[t][ks] = u.b;
      }
    }
  }
  f32x4 acc[2][NT];
#pragma unroll
  for (int t = 0; t < 2; t++)
#pragma unroll
    for (int nt = 0; nt < NT; nt++) acc[t][nt] = (f32x4){0.f, 0.f, 0.f, 0.f};
  const unsigned short* wf = Wfrag + (size_t)lane * 8;
#pragma unroll
  for (int ks = 0; ks < KSTEPS; ks++) {
#pragma unroll
    for (int nt = 0; nt < NT; nt++) {
      bf16x8 b = *reinterpret_cast<const bf16x8*>(wf + (size_t)(ks * NT + nt) * 512);
      acc[0][nt] = __builtin_amdgcn_mfma_f32_16x16x32_bf16(afrag[0][ks], b, acc[0][nt], 0, 0, 0);
      acc[1][nt] = __builtin_amdgcn_mfma_f32_16x16x32_bf16(afrag[1][ks], b, acc[1][nt], 0, 0, 0);
    }
  }
  const int rq = (lane >> 4) * 4;
#pragma unroll
  for (int t = 0; t < 2; t++) {
#pragma unroll
    for (int r = 0; r < 4; r++) {
      int row = base + t * 16 + rq + r;
      if (row < n) {
        float dv = dinv[row];
#pragma unroll
        for (int nt = 0; nt < NT; nt++) {
          int col = nt * 16 + (lane & 15);
          float v = acc[t][nt][r];
          if (col < C1) {
            O0[(size_t)row * S0 + col] = f2bf(v);
          } else if (col < C2) {
            O1[(size_t)row * S1 + (col - C1)] = f2bf(v);
          } else if (col < C3) {
            O2[(size_t)row * S2 + (col - C2)] = f2bf(v * dv);
          }
        }
      }
    }
  }
}

#define ACC8(A, d)                                   \
  {                                                  \
    A[0] += bflo(d.x); A[1] += bfhi(d.x);            \
    A[2] += bflo(d.y); A[3] += bfhi(d.y);            \
    A[4] += bflo(d.z); A[5] += bfhi(d.z);            \
    A[6] += bflo(d.w); A[7] += bfhi(d.w);            \
  }

// 4-nodes-per-wave CSR propagation: 16-lane quarter per node, 2 groups x 8
// lanes; group g gathers the full 128B row of edge j+2i+g as uint4; unroll
// x4 (4 gathers in flight); butterfly shfl_xor(8); epilogue on grp 0.
// addv is bf16 (stride AS). csr_src = pre-scaled row byte offsets.
//   G = sum_j g[src[j]]; v = addv - dinv[d]*G (+bias) (*dinv) (relu)
template <int F, int AS, int OS, bool RELU, bool BIAS, bool OUTSCALE, bool OBF16>
__global__ __launch_bounds__(256) void k_prop10(const unsigned short* __restrict__ g,
                                                const unsigned short* __restrict__ addv,
                                                const float* __restrict__ bias,
                                                const float* __restrict__ dinv,
                                                const int* __restrict__ csr_src,
                                                const int* __restrict__ row_ptr,
                                                void* __restrict__ outv, int n) {
  constexpr int SUBW = (F + 7) / 8;  // active 16B slots per row (8 or 5)
  const int lane = threadIdx.x & 63;
  const int wid = (blockIdx.x * blockDim.x + threadIdx.x) >> 6;
  const int node = wid * 4 + (lane >> 4);
  const int grp = (lane >> 3) & 1;
  const int sub = lane & 7;
  const bool valid = node < n;
  const int nd = valid ? node : (n - 1);
  const int beg = row_ptr[nd];
  const int end = valid ? row_ptr[nd + 1] : beg;
  const float dv = dinv[nd];
  const bool act = valid && ((SUBW == 8) || (sub < SUBW));
  const bool epi = (grp == 0) && act;
  // hoist epilogue operands (overlap with gather latency); addv is bf16
  float4 av0 = make_float4(0.f, 0.f, 0.f, 0.f), av1 = av0;
  if (epi) {
    const unsigned short* ap = addv + (size_t)nd * AS + sub * 8;
    uint4 a = *reinterpret_cast<const uint4*>(ap);
    av0 = make_float4(bflo(a.x), bfhi(a.x), bflo(a.y), bfhi(a.y));
    av1 = make_float4(bflo(a.z), bfhi(a.z), bflo(a.w), bfhi(a.w));
  }
  float acc[4][8];
#pragma unroll
  for (int i = 0; i < 4; i++)
#pragma unroll
    for (int k = 0; k < 8; k++) acc[i][k] = 0.f;
  if (act) {
    const char* gb = (const char*)g + sub * 16;
    int j = beg;
    for (; j + 8 <= end; j += 8) {
      int s0 = csr_src[j + grp];
      int s1 = csr_src[j + 2 + grp];
      int s2 = csr_src[j + 4 + grp];
      int s3 = csr_src[j + 6 + grp];
      uint4 d0 = *reinterpret_cast<const uint4*>(gb + s0);
      uint4 d1 = *reinterpret_cast<const uint4*>(gb + s1);
      uint4 d2 = *reinterpret_cast<const uint4*>(gb + s2);
      uint4 d3 = *reinterpret_cast<const uint4*>(gb + s3);
      ACC8(acc[0], d0);
      ACC8(acc[1], d1);
      ACC8(acc[2], d2);
      ACC8(acc[3], d3);
    }
    for (; j < end; j += 2) {
      int e = j + grp;
      int s0 = csr_src[min(e, end - 1)];
      uint4 d = *reinterpret_cast<const uint4*>(gb + s0);
      if (e >= end) { d.x = 0u; d.y = 0u; d.z = 0u; d.w = 0u; }
      ACC8(acc[0], d);
    }
  }
  float r[8];
#pragma unroll
  for (int k = 0; k < 8; k++)
    r[k] = (acc[0][k] + acc[1][k]) + (acc[2][k] + acc[3][k]);
#pragma unroll
  for (int k = 0; k < 8; k++) r[k] += __shfl_xor(r[k], 8);
  if (epi) {
    float v0 = av0.x - dv * r[0];
    float v1 = av0.y - dv * r[1];
    float v2 = av0.z - dv * r[2];
    float v3 = av0.w - dv * r[3];
    float v4 = av1.x - dv * r[4];
    float v5 = av1.y - dv * r[5];
    float v6 = av1.z - dv * r[6];
    float v7 = av1.w - dv * r[7];
    if (BIAS) {
      const float* bp = bias + sub * 8;
      float4 bv0 = *reinterpret_cast<const float4*>(bp);
      float4 bv1 = *reinterpret_cast<const float4*>(bp + 4);
      v0 += bv0.x; v1 += bv0.y; v2 += bv0.z; v3 += bv0.w;
      v4 += bv1.x; v5 += bv1.y; v6 += bv1.z; v7 += bv1.w;
    }
    if (OUTSCALE) {
      v0 *= dv; v1 *= dv; v2 *= dv; v3 *= dv;
      v4 *= dv; v5 *= dv; v6 *= dv; v7 *= dv;
    }
    if (RELU) {
      v0 = fmaxf(v0, 0.f); v1 = fmaxf(v1, 0.f); v2 = fmaxf(v2, 0.f); v3 = fmaxf(v3, 0.f);
      v4 = fmaxf(v4, 0.f); v5 = fmaxf(v5, 0.f); v6 = fmaxf(v6, 0.f); v7 = fmaxf(v7, 0.f);
    }
    if (OBF16) {
      uint4 o;
      o.x = pk2(v0, v1);
      o.y = pk2(v2, v3);
      o.z = pk2(v4, v5);
      o.w = pk2(v6, v7);
      *reinterpret_cast<uint4*>((unsigned short*)outv + (size_t)nd * OS + sub * 8) = o;
    } else {
      float* op = (float*)outv + (size_t)nd * OS + sub * 8;
      *reinterpret_cast<float4*>(op) = make_float4(v0, v1, v2, v3);
      *reinterpret_cast<float4*>(op + 4) = make_float4(v4, v5, v6, v7);
    }
  }
}

extern "C" void kernel_launch(void* const* d_in, const int* in_sizes, int n_in,
                              void* d_out, int out_size, void* d_ws, size_t ws_size,
                              hipStream_t stream) {
  const float* x  = (const float*)d_in[0];
  const int*   ei = (const int*)d_in[1];
  const float* W1 = (const float*)d_in[2];
  const float* b1 = (const float*)d_in[3];
  const float* W2 = (const float*)d_in[4];
  const float* b2 = (const float*)d_in[5];
  float* out = (float*)d_out;

  const int N = in_sizes[0] / 128;
  const int E = in_sizes[1] / 2;
  const int* src = ei;
  const int* dst = ei + E;

  const int nbuk = (N + 127) >> 7;
  if (nbuk > MAXBUK) return;
  const int cpb = (E + NBLK_PART - 1) / NBLK_PART;

  char* p = (char*)d_ws;
  size_t used = 0;
  auto alloc = [&](size_t bytes) -> void* {
    void* r = p + used;
    used += (bytes + 255) & ~(size_t)255;
    return r;
  };
  float* dinv    = (float*)alloc((size_t)N * 4);
  int*   row_ptr = (int*)alloc((size_t)(N + 1) * 4);
  int*   csr_src = (int*)alloc((size_t)E * 4);
  int*   buktotD = (int*)alloc((size_t)MAXBUK * 4);
  int*   buktotS = (int*)alloc((size_t)MAXBUK * 4);
  unsigned short* Wfrag1 = (unsigned short*)alloc((size_t)4 * 12 * 64 * 8 * 2);
  unsigned short* Wfrag2 = (unsigned short*)alloc((size_t)2 * 8 * 64 * 8 * 2);
  char* region = (char*)alloc((size_t)N * 512);                       // 51.2 MB
  unsigned short* hb = (unsigned short*)alloc((size_t)N * 64 * 2);    // 12.8 MB
  if (used > ws_size) return;

  // layer-1 layout in region (all bf16)
  unsigned short* Y0b  = (unsigned short*)region;                       // [N,64]
  unsigned short* Y1b  = (unsigned short*)(region + (size_t)N * 128);   // [N,64]
  unsigned short* Ys2b = (unsigned short*)(region + (size_t)N * 256);   // [N,64]
  unsigned short* Zsb  = (unsigned short*)(region + (size_t)N * 384);   // [N,64]
  // layer-2 layout aliases region (layer-1 dead by then)
  unsigned short* U0b  = (unsigned short*)region;                       // [N,40]
  unsigned short* U1b  = (unsigned short*)(region + (size_t)N * 80);    // [N,40]
  unsigned short* Us2b = (unsigned short*)(region + (size_t)N * 160);   // [N,64]
  unsigned short* Z2sb = (unsigned short*)(region + (size_t)N * 288);   // [N,64]
  // radix temporaries alias region (dead before gemm1)
  unsigned int* packed = (unsigned int*)region;                        // E*4
  unsigned char* pksrc = (unsigned char*)(region + (size_t)E * 4);     // E*1
  int* histGd = (int*)(region + (((size_t)E * 5 + 256 + 255) & ~(size_t)255));
  int* histGs = histGd + (size_t)MAXBUK * NBLK_PART;

  k_passA<<<NBLK_PART, 256, 0, stream>>>(src, dst, E, cpb, histGd, histGs, nbuk);
  k_scanA<<<2 * nbuk, 256, 0, stream>>>(histGd, histGs, buktotD, buktotS, nbuk);
  k_scanB<<<2, 256, 0, stream>>>(buktotD, buktotS, nbuk);
  k_passB<<<NBLK_PART, 256, 0, stream>>>(src, dst, E, cpb, histGd, histGs, buktotD, buktotS,
                                         nbuk, packed, pksrc);
  k_passCM<<<2 * nbuk, 256, 0, stream>>>(packed, pksrc, buktotD, buktotS, nbuk, E, N,
                                         csr_src, row_ptr, dinv);
  k_wfragM<<<(4 * 12 * 64 + 2 * 8 * 64 + 255) / 256, 256, 0, stream>>>(W1, Wfrag1, W2,
                                                                       Wfrag2);

  const int pb4 = ((size_t)N * 16 + 255) / 256;  // 4 nodes per wave
  const int gb2 = (N + 127) / 128;               // 2 row-tiles per wave

  // layer 1: [Y0b|Y1b|Ys2b] = bf16(x) @ Weff1 (Ys2 cols dinv-scaled)
  k_gemm_mfma<128, 12, false, 128, 64, 128, 192, 64, 64, 64>
      <<<gb2, 256, 0, stream>>>(x, Wfrag1, dinv, Y0b, Y1b, Ys2b, N);
  // Zs = dinv*(Y1 - dinv*G(Ys2))  -> bf16
  k_prop10<64, 64, 64, false, false, true, true><<<pb4, 256, 0, stream>>>(
      Ys2b, Y1b, nullptr, dinv, csr_src, row_ptr, Zsb, N);
  // h = relu(Y0 - dinv*G(Zs) + b1) -> bf16
  k_prop10<64, 64, 64, true, true, false, true><<<pb4, 256, 0, stream>>>(
      Zsb, Y0b, b1, dinv, csr_src, row_ptr, hb, N);
  // layer 2: [U0b|U1b|Us2b] = h @ Weff2 (Us2 cols dinv-scaled)
  k_gemm_mfma<64, 8, true, 64, 40, 80, 120, 40, 40, 64>
      <<<gb2, 256, 0, stream>>>(hb, Wfrag2, dinv, U0b, U1b, Us2b, N);
  // Z2s = dinv*(U1 - dinv*G(Us2)) -> bf16
  k_prop10<40, 40, 64, false, false, true, true><<<pb4, 256, 0, stream>>>(
      Us2b, U1b, nullptr, dinv, csr_src, row_ptr, Z2sb, N);
  // out = U0 - dinv*G(Z2s) + b2  (fp32)
  k_prop10<40, 40, 40, false, true, false, false><<<pb4, 256, 0, stream>>>(
      Z2sb, U0b, b2, dinv, csr_src, row_ptr, out, N);
}

// Round 15
// 254.895 us; speedup vs baseline: 1.0245x; 1.0245x over previous
//
#include <hip/hip_runtime.h>

// ChebConv x2: N=100000, E=1600000, K=3, IN=128, HID=64, OUT=40
// Round 15 = best-of-both:
//  - props: round-13 k_prop9 (2 nodes/wave, half-wave per node, 4 grp x 8
//    lanes, uint4 full-row gathers, unroll x2) — higher occupancy than r14's
//    4-node variant.
//  - GEMMs: round-14 LDS-free 2-row-tiles/wave (Wfrag stream halved).
//  - merged passCM + wfragM (round 14).
//  - CSR radix build w/ XCD-major cursors, bf16 residuals (rounds 12/13).

#define NBLK_PART 1024
#define MAXBUK 1024

typedef __attribute__((ext_vector_type(8))) short bf16x8;
typedef __attribute__((ext_vector_type(4))) float f32x4;

__device__ inline unsigned short f2bf(float f) {
  unsigned u = __float_as_uint(f);
  return (unsigned short)((u + 0x7FFFu + ((u >> 16) & 1u)) >> 16);
}
__device__ inline unsigned pk2(float a, float b) {
  return (unsigned)f2bf(a) | ((unsigned)f2bf(b) << 16);
}
__device__ inline float bflo(unsigned u) { return __uint_as_float(u << 16); }
__device__ inline float bfhi(unsigned u) { return __uint_as_float(u & 0xffff0000u); }

// XCD-major block permutation for cursor ranges (heuristic: XCD = b % 8)
__device__ inline int permb(int b) { return ((b & 7) << 7) | (b >> 3); }

// pass A: per-block LDS histograms of dst>>7 and src>>7 (no global atomics)
__global__ __launch_bounds__(256) void k_passA(const int* __restrict__ src,
                                               const int* __restrict__ dst, int E, int cpb,
                                               int* __restrict__ histGd,
                                               int* __restrict__ histGs, int nbuk) {
  __shared__ int histD[MAXBUK], histS[MAXBUK];
  const int t = threadIdx.x, b = blockIdx.x;
  for (int k = t; k < nbuk; k += 256) {
    histD[k] = 0;
    histS[k] = 0;
  }
  __syncthreads();
  const int e0 = b * cpb;
  const int e1 = min(E, e0 + cpb);
  for (int e = e0 + t; e < e1; e += 256) {
    atomicAdd(&histD[dst[e] >> 7], 1);
    atomicAdd(&histS[src[e] >> 7], 1);
  }
  __syncthreads();
  const int bp = permb(b);
  for (int k = t; k < nbuk; k += 256) {
    histGd[k * NBLK_PART + bp] = histD[k];
    histGs[k * NBLK_PART + bp] = histS[k];
  }
}

// per bucket: exclusive scan over the 1024 partition slots; grid = 2*nbuk
__global__ __launch_bounds__(256) void k_scanA(int* __restrict__ histGd,
                                               int* __restrict__ histGs,
                                               int* __restrict__ buktotD,
                                               int* __restrict__ buktotS, int nbuk) {
  __shared__ int sh[256];
  const int bb = blockIdx.x, t = threadIdx.x;
  int* hist = (bb < nbuk) ? histGd : histGs;
  int* tot = (bb < nbuk) ? buktotD : buktotS;
  const int b = (bb < nbuk) ? bb : bb - nbuk;
  const int base = b * NBLK_PART;
  int v[4];
  int s = 0;
#pragma unroll
  for (int i = 0; i < 4; i++) {
    v[i] = hist[base + t * 4 + i];
    s += v[i];
  }
  int run = s;
  sh[t] = run;
  __syncthreads();
  for (int off = 1; off < 256; off <<= 1) {
    int x = (t >= off) ? sh[t - off] : 0;
    __syncthreads();
    run += x;
    sh[t] = run;
    __syncthreads();
  }
  if (t == 255) tot[b] = run;
  int p = run - s;
#pragma unroll
  for (int i = 0; i < 4; i++) {
    hist[base + t * 4 + i] = p;
    p += v[i];
  }
}

// exclusive scan in place of two arrays (grid=2), nb <= 1024
__global__ __launch_bounds__(256) void k_scanB(int* __restrict__ aD, int* __restrict__ aS,
                                               int nb) {
  __shared__ int sh[256];
  int* a = (blockIdx.x == 0) ? aD : aS;
  const int t = threadIdx.x;
  int v[4];
  int s = 0;
#pragma unroll
  for (int i = 0; i < 4; i++) {
    int idx = t * 4 + i;
    v[i] = (idx < nb) ? a[idx] : 0;
    s += v[i];
  }
  int run = s;
  sh[t] = run;
  __syncthreads();
  for (int off = 1; off < 256; off <<= 1) {
    int x = (t >= off) ? sh[t - off] : 0;
    __syncthreads();
    run += x;
    sh[t] = run;
    __syncthreads();
  }
  int p = run - s;
#pragma unroll
  for (int i = 0; i < 4; i++) {
    int idx = t * 4 + i;
    if (idx < nb) a[idx] = p;
    p += v[i];
  }
}

// pass B: scatter (src<<7)|(dst&127) into dst-bucket order AND (src&127)
// bytes into src-bucket order, LDS cursors only; XCD-major cursor bases
__global__ __launch_bounds__(256) void k_passB(const int* __restrict__ src,
                                               const int* __restrict__ dst, int E, int cpb,
                                               const int* __restrict__ histGd,
                                               const int* __restrict__ histGs,
                                               const int* __restrict__ bukoffD,
                                               const int* __restrict__ bukoffS, int nbuk,
                                               unsigned int* __restrict__ packed,
                                               unsigned char* __restrict__ pksrc) {
  __shared__ int curD[MAXBUK], curS[MAXBUK];
  const int t = threadIdx.x, b = blockIdx.x;
  const int bp = permb(b);
  for (int k = t; k < nbuk; k += 256) {
    curD[k] = bukoffD[k] + histGd[k * NBLK_PART + bp];
    curS[k] = bukoffS[k] + histGs[k * NBLK_PART + bp];
  }
  __syncthreads();
  const int e0 = b * cpb;
  const int e1 = min(E, e0 + cpb);
  for (int e = e0 + t; e < e1; e += 256) {
    int s = src[e], d = dst[e];
    int slot = atomicAdd(&curD[d >> 7], 1);
    packed[slot] = ((unsigned)s << 7) | (unsigned)(d & 127);
    int slot2 = atomicAdd(&curS[s >> 7], 1);
    pksrc[slot2] = (unsigned char)(s & 127);
  }
}

// merged pass C (blocks [0,nbuk): CSR finalize from dst buckets) and
// pass C2 (blocks [nbuk,2nbuk): dinv from src-bucket bytes)
__global__ __launch_bounds__(256) void k_passCM(const unsigned int* __restrict__ packed,
                                                const unsigned char* __restrict__ pksrc,
                                                const int* __restrict__ bukoffD,
                                                const int* __restrict__ bukoffS, int nbuk,
                                                int E, int n, int* __restrict__ csr_src,
                                                int* __restrict__ row_ptr,
                                                float* __restrict__ dinv) {
  __shared__ int cnt[128], scn[128], cur[128];
  const int t = threadIdx.x;
  if (blockIdx.x < nbuk) {
    const int b = blockIdx.x;
    if (t < 128) cnt[t] = 0;
    __syncthreads();
    const int e0 = bukoffD[b];
    const int e1 = (b + 1 < nbuk) ? bukoffD[b + 1] : E;
    for (int e = e0 + t; e < e1; e += 256) atomicAdd(&cnt[packed[e] & 127], 1);
    __syncthreads();
    if (t < 128) scn[t] = cnt[t];
    __syncthreads();
    for (int off = 1; off < 128; off <<= 1) {
      int x = (t < 128 && t >= off) ? scn[t - off] : 0;
      __syncthreads();
      if (t < 128) scn[t] += x;
      __syncthreads();
    }
    if (t < 128) {
      int start = e0 + scn[t] - cnt[t];
      cur[t] = start;
      int node = (b << 7) + t;
      if (node < n) row_ptr[node] = start;
    }
    if (b == 0 && t == 0) row_ptr[n] = E;
    __syncthreads();
    for (int e = e0 + t; e < e1; e += 256) {
      unsigned v = packed[e];
      int slot = atomicAdd(&cur[v & 127], 1);
      csr_src[slot] = (int)(v & ~127u);  // src*128 = byte offset of bf16[64] row
    }
  } else {
    const int b = blockIdx.x - nbuk;
    if (t < 128) cnt[t] = 0;
    __syncthreads();
    const int e0 = bukoffS[b];
    const int e1 = (b + 1 < nbuk) ? bukoffS[b + 1] : E;
    for (int e = e0 + t; e < e1; e += 256) atomicAdd(&cnt[pksrc[e]], 1);
    __syncthreads();
    if (t < 128) {
      int node = (b << 7) + t;
      if (node < n) {
        int d = cnt[t];
        dinv[node] = (d > 0) ? rsqrtf((float)d) : 0.f;
      }
    }
  }
}

// pre-swizzle effective weights into MFMA B-fragment order, bf16 (merged)
__device__ inline void wfrag_emit(const float* __restrict__ W,
                                  unsigned short* __restrict__ Wfrag, int INF, int OUTC,
                                  int NT, int idx) {
  int lane = idx & 63;
  int nt = (idx >> 6) % NT;
  int ks = idx / (64 * NT);
  int col = nt * 16 + (lane & 15);
  int kb = ks * 32 + (lane >> 4) * 8;
  unsigned short o8[8];
#pragma unroll
  for (int j = 0; j < 8; j++) {
    int k = kb + j;
    float v = 0.f;
    if (col < 3 * OUTC) {
      int m = col / OUTC, o = col - m * OUTC;
      if (m == 0)      v = W[(0 * INF + k) * OUTC + o] - W[(2 * INF + k) * OUTC + o];
      else if (m == 1) v = W[(1 * INF + k) * OUTC + o];
      else             v = 2.f * W[(2 * INF + k) * OUTC + o];
    }
    o8[j] = f2bf(v);
  }
  uint4 r;
  r.x = (unsigned)o8[0] | ((unsigned)o8[1] << 16);
  r.y = (unsigned)o8[2] | ((unsigned)o8[3] << 16);
  r.z = (unsigned)o8[4] | ((unsigned)o8[5] << 16);
  r.w = (unsigned)o8[6] | ((unsigned)o8[7] << 16);
  *reinterpret_cast<uint4*>(Wfrag + (size_t)idx * 8) = r;
}

__global__ void k_wfragM(const float* __restrict__ W1, unsigned short* __restrict__ Wf1,
                         const float* __restrict__ W2, unsigned short* __restrict__ Wf2) {
  int idx = blockIdx.x * 256 + threadIdx.x;
  const int tot1 = 4 * 12 * 64;
  const int tot2 = 2 * 8 * 64;
  if (idx < tot1)
    wfrag_emit(W1, Wf1, 128, 64, 12, idx);
  else if (idx < tot1 + tot2)
    wfrag_emit(W2, Wf2, 64, 40, 8, idx - tot1);
}

// LDS-free MFMA GEMM, 2 row-tiles per wave (32 rows), all-bf16 split epilogue:
//   each Wfrag B-fragment load feeds 2 MFMAs.
template <int INF, int NT, bool XBF16, int XSTR, int C1, int C2, int C3, int S0, int S1,
          int S2>
__global__ __launch_bounds__(256) void k_gemm_mfma(const void* __restrict__ Xv,
                                                   const unsigned short* __restrict__ Wfrag,
                                                   const float* __restrict__ dinv,
                                                   unsigned short* __restrict__ O0,
                                                   unsigned short* __restrict__ O1,
                                                   unsigned short* __restrict__ O2, int n) {
  constexpr int KSTEPS = INF / 32;
  const int lane = threadIdx.x & 63;
  const int w = threadIdx.x >> 6;
  const int base = blockIdx.x * 128 + 32 * w;  // this wave's 32-row tile
  const int k8 = (lane >> 4) * 8;
  union U16 {
    uint4 u;
    bf16x8 b;
  };
  bf16x8 afrag[2][KSTEPS];
#pragma unroll
  for (int t = 0; t < 2; t++) {
    const int arow = base + t * 16 + (lane & 15);
    const bool ok = arow < n;
    if (XBF16) {
      const unsigned short* sp =
          (const unsigned short*)Xv + (size_t)(ok ? arow : 0) * XSTR + k8;
#pragma unroll
      for (int ks = 0; ks < KSTEPS; ks++) {
        U16 u;
        u.u = make_uint4(0, 0, 0, 0);
        if (ok) u.u = *reinterpret_cast<const uint4*>(sp + ks * 32);
        afrag[t][ks] = u.b;
      }
    } else {
      const float* sp = (const float*)Xv + (size_t)(ok ? arow : 0) * XSTR + k8;
#pragma unroll
      for (int ks = 0; ks < KSTEPS; ks++) {
        float4 va = make_float4(0.f, 0.f, 0.f, 0.f), vb = va;
        if (ok) {
          va = *reinterpret_cast<const float4*>(sp + ks * 32);
          vb = *reinterpret_cast<const float4*>(sp + ks * 32 + 4);
        }
        U16 u;
        u.u.x = pk2(va.x, va.y);
        u.u.y = pk2(va.z, va.w);
        u.u.z = pk2(vb.x, vb.y);
        u.u.w = pk2(vb.z, vb.w);
        afrag[t][ks] = u.b;
      }
    }
  }
  f32x4 acc[2][NT];
#pragma unroll
  for (int t = 0; t < 2; t++)
#pragma unroll
    for (int nt = 0; nt < NT; nt++) acc[t][nt] = (f32x4){0.f, 0.f, 0.f, 0.f};
  const unsigned short* wf = Wfrag + (size_t)lane * 8;
#pragma unroll
  for (int ks = 0; ks < KSTEPS; ks++) {
#pragma unroll
    for (int nt = 0; nt < NT; nt++) {
      bf16x8 b = *reinterpret_cast<const bf16x8*>(wf + (size_t)(ks * NT + nt) * 512);
      acc[0][nt] = __builtin_amdgcn_mfma_f32_16x16x32_bf16(afrag[0][ks], b, acc[0][nt], 0, 0, 0);
      acc[1][nt] = __builtin_amdgcn_mfma_f32_16x16x32_bf16(afrag[1][ks], b, acc[1][nt], 0, 0, 0);
    }
  }
  const int rq = (lane >> 4) * 4;
#pragma unroll
  for (int t = 0; t < 2; t++) {
#pragma unroll
    for (int r = 0; r < 4; r++) {
      int row = base + t * 16 + rq + r;
      if (row < n) {
        float dv = dinv[row];
#pragma unroll
        for (int nt = 0; nt < NT; nt++) {
          int col = nt * 16 + (lane & 15);
          float v = acc[t][nt][r];
          if (col < C1) {
            O0[(size_t)row * S0 + col] = f2bf(v);
          } else if (col < C2) {
            O1[(size_t)row * S1 + (col - C1)] = f2bf(v);
          } else if (col < C3) {
            O2[(size_t)row * S2 + (col - C2)] = f2bf(v * dv);
          }
        }
      }
    }
  }
}

// 2-nodes-per-wave CSR propagation (round 13): half-wave per node, 4 groups
// x 8 lanes; group g gathers the full 128B row of edge j+g as uint4; unroll
// x2; bf16 extract+add; butterfly shfl_xor(8/16); epilogue grp 0.
// addv is bf16 (stride AS). csr_src = pre-scaled row byte offsets.
//   G = sum_j g[src[j]]; v = addv - dinv[d]*G (+bias) (*dinv) (relu)
template <int F, int AS, int OS, bool RELU, bool BIAS, bool OUTSCALE, bool OBF16>
__global__ __launch_bounds__(256) void k_prop9(const unsigned short* __restrict__ g,
                                               const unsigned short* __restrict__ addv,
                                               const float* __restrict__ bias,
                                               const float* __restrict__ dinv,
                                               const int* __restrict__ csr_src,
                                               const int* __restrict__ row_ptr,
                                               void* __restrict__ outv, int n) {
  constexpr int SUBW = (F + 7) / 8;  // active 16B slots per row (8 or 5)
  const int lane = threadIdx.x & 63;
  const int wid = (blockIdx.x * blockDim.x + threadIdx.x) >> 6;
  const int node = wid * 2 + (lane >> 5);
  const int grp = (lane >> 3) & 3;
  const int sub = lane & 7;
  const bool valid = node < n;
  const int nd = valid ? node : (n - 1);
  const int beg = row_ptr[nd];
  const int end = valid ? row_ptr[nd + 1] : beg;
  const float dv = dinv[nd];
  const bool act = valid && ((SUBW == 8) || (sub < SUBW));
  const bool epi = (grp == 0) && act;
  // hoist epilogue operands (overlap with gather latency); addv is bf16
  float4 av0 = make_float4(0.f, 0.f, 0.f, 0.f), av1 = av0;
  if (epi) {
    const unsigned short* ap = addv + (size_t)nd * AS + sub * 8;
    uint4 a = *reinterpret_cast<const uint4*>(ap);
    av0 = make_float4(bflo(a.x), bfhi(a.x), bflo(a.y), bfhi(a.y));
    av1 = make_float4(bflo(a.z), bfhi(a.z), bflo(a.w), bfhi(a.w));
  }
  float a0 = 0.f, a1 = 0.f, a2 = 0.f, a3 = 0.f, a4 = 0.f, a5 = 0.f, a6 = 0.f, a7 = 0.f;
  float c0 = 0.f, c1 = 0.f, c2 = 0.f, c3 = 0.f, c4 = 0.f, c5 = 0.f, c6 = 0.f, c7 = 0.f;
  if (act) {
    const char* gb = (const char*)g + sub * 16;
    int j = beg;
    for (; j + 8 <= end; j += 8) {
      int sA = csr_src[j + grp];
      int sB = csr_src[j + 4 + grp];
      uint4 dA = *reinterpret_cast<const uint4*>(gb + sA);
      uint4 dB = *reinterpret_cast<const uint4*>(gb + sB);
      a0 += bflo(dA.x); a1 += bfhi(dA.x); a2 += bflo(dA.y); a3 += bfhi(dA.y);
      a4 += bflo(dA.z); a5 += bfhi(dA.z); a6 += bflo(dA.w); a7 += bfhi(dA.w);
      c0 += bflo(dB.x); c1 += bfhi(dB.x); c2 += bflo(dB.y); c3 += bfhi(dB.y);
      c4 += bflo(dB.z); c5 += bfhi(dB.z); c6 += bflo(dB.w); c7 += bfhi(dB.w);
    }
    for (; j < end; j += 4) {
      int e = j + grp;
      int s0 = csr_src[min(e, end - 1)];
      uint4 d = *reinterpret_cast<const uint4*>(gb + s0);
      if (e >= end) { d.x = 0u; d.y = 0u; d.z = 0u; d.w = 0u; }
      a0 += bflo(d.x); a1 += bfhi(d.x); a2 += bflo(d.y); a3 += bfhi(d.y);
      a4 += bflo(d.z); a5 += bfhi(d.z); a6 += bflo(d.w); a7 += bfhi(d.w);
    }
  }
  float r0 = a0 + c0, r1 = a1 + c1, r2 = a2 + c2, r3 = a3 + c3;
  float r4 = a4 + c4, r5 = a5 + c5, r6 = a6 + c6, r7 = a7 + c7;
#pragma unroll
  for (int m = 8; m < 32; m <<= 1) {
    r0 += __shfl_xor(r0, m); r1 += __shfl_xor(r1, m);
    r2 += __shfl_xor(r2, m); r3 += __shfl_xor(r3, m);
    r4 += __shfl_xor(r4, m); r5 += __shfl_xor(r5, m);
    r6 += __shfl_xor(r6, m); r7 += __shfl_xor(r7, m);
  }
  if (epi) {
    float v0 = av0.x - dv * r0;
    float v1 = av0.y - dv * r1;
    float v2 = av0.z - dv * r2;
    float v3 = av0.w - dv * r3;
    float v4 = av1.x - dv * r4;
    float v5 = av1.y - dv * r5;
    float v6 = av1.z - dv * r6;
    float v7 = av1.w - dv * r7;
    if (BIAS) {
      const float* bp = bias + sub * 8;
      float4 bv0 = *reinterpret_cast<const float4*>(bp);
      float4 bv1 = *reinterpret_cast<const float4*>(bp + 4);
      v0 += bv0.x; v1 += bv0.y; v2 += bv0.z; v3 += bv0.w;
      v4 += bv1.x; v5 += bv1.y; v6 += bv1.z; v7 += bv1.w;
    }
    if (OUTSCALE) {
      v0 *= dv; v1 *= dv; v2 *= dv; v3 *= dv;
      v4 *= dv; v5 *= dv; v6 *= dv; v7 *= dv;
    }
    if (RELU) {
      v0 = fmaxf(v0, 0.f); v1 = fmaxf(v1, 0.f); v2 = fmaxf(v2, 0.f); v3 = fmaxf(v3, 0.f);
      v4 = fmaxf(v4, 0.f); v5 = fmaxf(v5, 0.f); v6 = fmaxf(v6, 0.f); v7 = fmaxf(v7, 0.f);
    }
    if (OBF16) {
      uint4 o;
      o.x = pk2(v0, v1);
      o.y = pk2(v2, v3);
      o.z = pk2(v4, v5);
      o.w = pk2(v6, v7);
      *reinterpret_cast<uint4*>((unsigned short*)outv + (size_t)nd * OS + sub * 8) = o;
    } else {
      float* op = (float*)outv + (size_t)nd * OS + sub * 8;
      *reinterpret_cast<float4*>(op) = make_float4(v0, v1, v2, v3);
      *reinterpret_cast<float4*>(op + 4) = make_float4(v4, v5, v6, v7);
    }
  }
}

extern "C" void kernel_launch(void* const* d_in, const int* in_sizes, int n_in,
                              void* d_out, int out_size, void* d_ws, size_t ws_size,
                              hipStream_t stream) {
  const float* x  = (const float*)d_in[0];
  const int*   ei = (const int*)d_in[1];
  const float* W1 = (const float*)d_in[2];
  const float* b1 = (const float*)d_in[3];
  const float* W2 = (const float*)d_in[4];
  const float* b2 = (const float*)d_in[5];
  float* out = (float*)d_out;

  const int N = in_sizes[0] / 128;
  const int E = in_sizes[1] / 2;
  const int* src = ei;
  const int* dst = ei + E;

  const int nbuk = (N + 127) >> 7;
  if (nbuk > MAXBUK) return;
  const int cpb = (E + NBLK_PART - 1) / NBLK_PART;

  char* p = (char*)d_ws;
  size_t used = 0;
  auto alloc = [&](size_t bytes) -> void* {
    void* r = p + used;
    used += (bytes + 255) & ~(size_t)255;
    return r;
  };
  float* dinv    = (float*)alloc((size_t)N * 4);
  int*   row_ptr = (int*)alloc((size_t)(N + 1) * 4);
  int*   csr_src = (int*)alloc((size_t)E * 4);
  int*   buktotD = (int*)alloc((size_t)MAXBUK * 4);
  int*   buktotS = (int*)alloc((size_t)MAXBUK * 4);
  unsigned short* Wfrag1 = (unsigned short*)alloc((size_t)4 * 12 * 64 * 8 * 2);
  unsigned short* Wfrag2 = (unsigned short*)alloc((size_t)2 * 8 * 64 * 8 * 2);
  char* region = (char*)alloc((size_t)N * 512);                       // 51.2 MB
  unsigned short* hb = (unsigned short*)alloc((size_t)N * 64 * 2);    // 12.8 MB
  if (used > ws_size) return;

  // layer-1 layout in region (all bf16)
  unsigned short* Y0b  = (unsigned short*)region;                       // [N,64]
  unsigned short* Y1b  = (unsigned short*)(region + (size_t)N * 128);   // [N,64]
  unsigned short* Ys2b = (unsigned short*)(region + (size_t)N * 256);   // [N,64]
  unsigned short* Zsb  = (unsigned short*)(region + (size_t)N * 384);   // [N,64]
  // layer-2 layout aliases region (layer-1 dead by then)
  unsigned short* U0b  = (unsigned short*)region;                       // [N,40]
  unsigned short* U1b  = (unsigned short*)(region + (size_t)N * 80);    // [N,40]
  unsigned short* Us2b = (unsigned short*)(region + (size_t)N * 160);   // [N,64]
  unsigned short* Z2sb = (unsigned short*)(region + (size_t)N * 288);   // [N,64]
  // radix temporaries alias region (dead before gemm1)
  unsigned int* packed = (unsigned int*)region;                        // E*4
  unsigned char* pksrc = (unsigned char*)(region + (size_t)E * 4);     // E*1
  int* histGd = (int*)(region + (((size_t)E * 5 + 256 + 255) & ~(size_t)255));
  int* histGs = histGd + (size_t)MAXBUK * NBLK_PART;

  k_passA<<<NBLK_PART, 256, 0, stream>>>(src, dst, E, cpb, histGd, histGs, nbuk);
  k_scanA<<<2 * nbuk, 256, 0, stream>>>(histGd, histGs, buktotD, buktotS, nbuk);
  k_scanB<<<2, 256, 0, stream>>>(buktotD, buktotS, nbuk);
  k_passB<<<NBLK_PART, 256, 0, stream>>>(src, dst, E, cpb, histGd, histGs, buktotD, buktotS,
                                         nbuk, packed, pksrc);
  k_passCM<<<2 * nbuk, 256, 0, stream>>>(packed, pksrc, buktotD, buktotS, nbuk, E, N,
                                         csr_src, row_ptr, dinv);
  k_wfragM<<<(4 * 12 * 64 + 2 * 8 * 64 + 255) / 256, 256, 0, stream>>>(W1, Wfrag1, W2,
                                                                       Wfrag2);

  const int pb2 = ((size_t)N * 32 + 255) / 256;  // 2 nodes per wave
  const int gb2 = (N + 127) / 128;               // 2 row-tiles per wave

  // layer 1: [Y0b|Y1b|Ys2b] = bf16(x) @ Weff1 (Ys2 cols dinv-scaled)
  k_gemm_mfma<128, 12, false, 128, 64, 128, 192, 64, 64, 64>
      <<<gb2, 256, 0, stream>>>(x, Wfrag1, dinv, Y0b, Y1b, Ys2b, N);
  // Zs = dinv*(Y1 - dinv*G(Ys2))  -> bf16
  k_prop9<64, 64, 64, false, false, true, true><<<pb2, 256, 0, stream>>>(
      Ys2b, Y1b, nullptr, dinv, csr_src, row_ptr, Zsb, N);
  // h = relu(Y0 - dinv*G(Zs) + b1) -> bf16
  k_prop9<64, 64, 64, true, true, false, true><<<pb2, 256, 0, stream>>>(
      Zsb, Y0b, b1, dinv, csr_src, row_ptr, hb, N);
  // layer 2: [U0b|U1b|Us2b] = h @ Weff2 (Us2 cols dinv-scaled)
  k_gemm_mfma<64, 8, true, 64, 40, 80, 120, 40, 40, 64>
      <<<gb2, 256, 0, stream>>>(hb, Wfrag2, dinv, U0b, U1b, Us2b, N);
  // Z2s = dinv*(U1 - dinv*G(Us2)) -> bf16
  k_prop9<40, 40, 64, false, false, true, true><<<pb2, 256, 0, stream>>>(
      Us2b, U1b, nullptr, dinv, csr_src, row_ptr, Z2sb, N);
  // out = U0 - dinv*G(Z2s) + b2  (fp32)
  k_prop9<40, 40, 40, false, true, false, false><<<pb2, 256, 0, stream>>>(
      Z2sb, U0b, b2, dinv, csr_src, row_ptr, out, N);
}